// Round 3
// baseline (973.706 us; speedup 1.0000x reference)
//
#include <hip/hip_runtime.h>

#define B_ 8
#define T_ 1024
#define C_ 1024
#define E_ 8
#define H_ 4096

typedef float v4f __attribute__((ext_vector_type(4)));
typedef short v8s __attribute__((ext_vector_type(8)));

__device__ __forceinline__ unsigned short f2bf(float f) {
  union { float f; unsigned int u; } x; x.f = f;
  unsigned int r = x.u + 0x7fffu + ((x.u >> 16) & 1u);
  return (unsigned short)(r >> 16);
}

__device__ __forceinline__ void async_load16(const unsigned short* g, unsigned short* l) {
  __builtin_amdgcn_global_load_lds(
      (const __attribute__((address_space(1))) void*)g,
      (__attribute__((address_space(3))) void*)l, 16, 0, 0);
}

// ---------------- router phase (unchanged) ----------------

__global__ void k_meanpart(const float* __restrict__ x, float* __restrict__ part,
                           unsigned short* __restrict__ xb) {
  int b = blockIdx.x >> 5, tc = blockIdx.x & 31;
  int c4 = threadIdx.x * 4;
  const size_t base = (size_t)b * T_ * C_ + (size_t)tc * 32 * C_ + c4;
  const float* xp = x + base;
  v4f s = {0.f, 0.f, 0.f, 0.f};
  for (int t = 0; t < 32; ++t) {
    v4f v = *(const v4f*)(xp + (size_t)t * C_);
    s += v;
    ushort4 o;
    o.x = f2bf(v.x); o.y = f2bf(v.y); o.z = f2bf(v.z); o.w = f2bf(v.w);
    *(ushort4*)(xb + base + (size_t)t * C_) = o;
  }
  *(v4f*)(part + (size_t)(tc * B_ + b) * C_ + c4) = s;
}

__global__ void k_router(const float* __restrict__ part, const float* __restrict__ rw,
                         int* __restrict__ sel, float* __restrict__ wv,
                         float* __restrict__ loss_out) {
  __shared__ float seq[B_ * C_];
  __shared__ float red[B_ * E_][4];
  __shared__ float pr[B_][E_];
  __shared__ int ss[B_][2];
  const int tid = threadIdx.x;
  for (int idx = tid; idx < B_ * C_; idx += 256) {
    float s = 0.f;
#pragma unroll
    for (int tc = 0; tc < 32; ++tc) s += part[(size_t)tc * B_ * C_ + idx];
    seq[idx] = s * (1.0f / T_);
  }
  __syncthreads();
  {
    int pair = tid >> 2, sub = tid & 3;
    int b = pair >> 3, e = pair & 7;
    float acc = 0.f;
    const float* sp = seq + b * C_ + sub * 256;
    const float* wp = rw + e * C_ + sub * 256;
    for (int c = 0; c < 256; ++c) acc += sp[c] * wp[c];
    red[pair][sub] = acc;
  }
  __syncthreads();
  if (tid < B_ * E_)
    pr[tid >> 3][tid & 7] = red[tid][0] + red[tid][1] + red[tid][2] + red[tid][3];
  __syncthreads();
  if (tid < B_) {
    int b = tid;
    float mx = pr[b][0];
#pragma unroll
    for (int e = 1; e < E_; ++e) mx = fmaxf(mx, pr[b][e]);
    float p[E_]; float sum = 0.f;
#pragma unroll
    for (int e = 0; e < E_; ++e) { p[e] = __expf(pr[b][e] - mx); sum += p[e]; }
    float inv = 1.0f / sum;
#pragma unroll
    for (int e = 0; e < E_; ++e) { p[e] *= inv; pr[b][e] = p[e]; }
    int i0 = 0;
#pragma unroll
    for (int e = 1; e < E_; ++e) if (p[e] > p[i0]) i0 = e;
    int i1 = (i0 == 0) ? 1 : 0;
#pragma unroll
    for (int e = 0; e < E_; ++e) if (e != i0 && p[e] > p[i1]) i1 = e;
    float s2 = p[i0] + p[i1];
    sel[b * 2 + 0] = i0; sel[b * 2 + 1] = i1;
    wv[b * 2 + 0] = p[i0] / s2; wv[b * 2 + 1] = p[i1] / s2;
    ss[b][0] = i0; ss[b][1] = i1;
  }
  __syncthreads();
  if (tid == 0) {
    float loss = 0.f;
    for (int e = 0; e < E_; ++e) {
      float imp = 0.f, ld = 0.f;
      for (int b = 0; b < B_; ++b) {
        imp += pr[b][e];
        ld += ((ss[b][0] == e) || (ss[b][1] == e)) ? 1.f : 0.f;
      }
      loss += (imp / (float)B_) * (ld / (float)B_);
    }
    loss_out[0] = loss * (float)E_;
  }
}

// ---------------- transpose+cast (unchanged) ----------------
__global__ void k_transpose(const float* __restrict__ src, unsigned short* __restrict__ dst,
                            int R, int Cc) {
  __shared__ float tile[64][65];
  const size_t sl = (size_t)blockIdx.z * R * Cc;
  int c0 = blockIdx.x * 64, r0 = blockIdx.y * 64;
  int tx = threadIdx.x & 15, ty = threadIdx.x >> 4;
#pragma unroll
  for (int p = 0; p < 4; ++p) {
    int r = p * 16 + ty;
    v4f v = *(const v4f*)(src + sl + (size_t)(r0 + r) * Cc + c0 + tx * 4);
    tile[r][tx * 4 + 0] = v.x; tile[r][tx * 4 + 1] = v.y;
    tile[r][tx * 4 + 2] = v.z; tile[r][tx * 4 + 3] = v.w;
  }
  __syncthreads();
#pragma unroll
  for (int p = 0; p < 4; ++p) {
    int c = p * 16 + ty;
    int rr = tx * 4;
    ushort4 o;
    o.x = f2bf(tile[rr + 0][c]); o.y = f2bf(tile[rr + 1][c]);
    o.z = f2bf(tile[rr + 2][c]); o.w = f2bf(tile[rr + 3][c]);
    *(ushort4*)(dst + sl + (size_t)(c0 + c) * R + r0 + rr) = o;
  }
}

// ---------------- 256x256 8-phase GEMM core, ahead-1 fragment prefetch ----------------
// LDS (shorts): buf d at d*32768; regions: A-lo 0, A-hi 8192, B-lo 16384, B-hi 24576.
// Region = 128 rows x 64 cols bf16; chunk c of row r stored at chunk c ^ (r&7)
// (pre-swizzled global source, linear LDS dest; swizzled ds_read).
// Per iteration (tiles t0=buf0, t1=buf1), consumption Q00,Q10,Q01,Q11 per tile.
// Every ds_read lands >=1 phase before its QUAD (iteration-start frags land in
// P7/P8 of the PREVIOUS iteration).  Stage schedule: P1:A(t1)x2  P3:Blo(t0')
// P4:Bhi(t0')  P5:A(t0')x2  P7:Blo(t1')  P8:Bhi(t1').
//
// CROSS-WAVE HANDSHAKE (round-2 bug fix): vmcnt(N) only observes MY wave's
// staging loads; a region is safe to ds_read only after (every wave's vmcnt
// wait) + barrier.  So each counted wait sits BETWEEN its phase's QUAD and the
// CLOSING barrier; dependent reads are issued after that barrier, pinned by
// sched_barrier(0) so the compiler cannot hoist them into the pre-barrier
// window.  Ledger (loads oldest-first), verified closed: enter {B(t1)}=4;
// P1 stage A(t1)+4 =8; in-P2 vmcnt(4)->B(t1) landed; P3 +2(Blo t0');
// in-P3 vmcnt(2)->A(t1) landed; P4 +2(Bhi t0'); P5 +4(A t0');
// in-P6 vmcnt(4)->B(t0') landed; P7 +2(Blo t1'); in-P7 vmcnt(2)->A(t0')
// landed; P8 +2(Bhi t1'); exit {B(t1')}=4 = entry.  All reads behind
// wait+barrier; all LDS overwrites keep >=3-phase margin vs last read.

#define BAR()  __builtin_amdgcn_s_barrier()
#define SCH0() __builtin_amdgcn_sched_barrier(0)
#define VMC4() asm volatile("s_waitcnt vmcnt(4)" ::: "memory")
#define VMC2() asm volatile("s_waitcnt vmcnt(2)" ::: "memory")
#define VMC0() asm volatile("s_waitcnt vmcnt(0)" ::: "memory")

__device__ __forceinline__ void gemm256(const unsigned short* __restrict__ Ag,
                                        const unsigned short* __restrict__ Bg,
                                        int lda, int ldb, int Kd,
                                        unsigned short* LDS, v4f (&acc)[8][4]) {
  const int tid = threadIdx.x;
  const int lane = tid & 63;
  const int w = __builtin_amdgcn_readfirstlane(tid >> 6);
  const int wm = w >> 2, wn = w & 3;
  const int rr = lane & 15, q = lane >> 4, s7 = rr & 7;
  const int ck0 = (q ^ s7) * 8;
  const int ck1 = ((4 | q) ^ s7) * 8;
  const int aoff = wm * 8192 + rr * 64;
  const int boff = 16384 + (wn >> 1) * 8192 + (wn & 1) * 4096 + rr * 64;
  const int w8 = w * 8;
  const int l3 = lane >> 3;
  const int srow = w8 + l3;
  const int sel8 = ((lane & 7) ^ l3) * 8;
  v8s afA[4][2], afB[4][2];
  v8s bP0[2][2], bP1[2][2], bP2[2][2], bP3[2][2];

#define STG(gb, ld, reg) do { \
    const unsigned short* _g = (gb) + (size_t)srow * (ld) + sel8; \
    async_load16(_g, LDS + (reg) + w8 * 64); \
    async_load16(_g + (size_t)64 * (ld), LDS + (reg) + 4096 + w8 * 64); \
  } while (0)

#define RDA(dst, qi, bs) do { \
    _Pragma("unroll") for (int _i = 0; _i < 4; ++_i) { \
      dst[_i][0] = *(const v8s*)&LDS[(bs) + aoff + ((qi)*4+_i)*1024 + ck0]; \
      dst[_i][1] = *(const v8s*)&LDS[(bs) + aoff + ((qi)*4+_i)*1024 + ck1]; \
    } } while (0)

#define RDBP(dst, qj, bs) do { \
    _Pragma("unroll") for (int _j = 0; _j < 2; ++_j) { \
      dst[_j][0] = *(const v8s*)&LDS[(bs) + boff + ((qj)*2+_j)*1024 + ck0]; \
      dst[_j][1] = *(const v8s*)&LDS[(bs) + boff + ((qj)*2+_j)*1024 + ck1]; \
    } } while (0)

#define QUAD(qi, AF, BP, qj) do { \
    __builtin_amdgcn_s_setprio(1); \
    _Pragma("unroll") for (int _k = 0; _k < 2; ++_k) \
    _Pragma("unroll") for (int _i = 0; _i < 4; ++_i) \
    _Pragma("unroll") for (int _j = 0; _j < 2; ++_j) \
      acc[(qi)*4+_i][(qj)*2+_j] = __builtin_amdgcn_mfma_f32_16x16x32_bf16( \
          AF[_i][_k], BP[_j][_k], acc[(qi)*4+_i][(qj)*2+_j], 0, 0, 0); \
    __builtin_amdgcn_s_setprio(0); \
  } while (0)

#define ITER(k0, LAST) do { \
    /* P1: prefetch A(t0,q1); stage A(t1) both halves */ \
    RDA(afB, 1, 0); \
    STG(Ag + (k0) + 64, lda, 32768 + 0); \
    STG(Ag + (size_t)128 * lda + (k0) + 64, lda, 32768 + 8192); \
    SCH0(); BAR(); QUAD(0, afA, bP0, 0); BAR(); \
    /* P2: wait B(t1) then closing barrier (gates P3 reads) */ \
    BAR(); QUAD(1, afB, bP0, 0); VMC4(); BAR(); SCH0(); \
    /* P3: prefetch B(t1,01); stage B-lo(t0'); wait A(t1) */ \
    RDBP(bP2, 0, 32768); \
    if (!(LAST)) STG(Bg + (k0) + 128, ldb, 16384); \
    SCH0(); BAR(); QUAD(0, afA, bP1, 1); \
    if (LAST) { VMC0(); } else { VMC2(); } \
    BAR(); SCH0(); \
    /* P4: prefetch B(t1,23)+A(t1,q0); stage B-hi(t0') */ \
    RDBP(bP3, 1, 32768); \
    RDA(afA, 0, 32768); \
    if (!(LAST)) STG(Bg + (size_t)128 * ldb + (k0) + 128, ldb, 24576); \
    SCH0(); BAR(); QUAD(1, afB, bP1, 1); BAR(); \
    /* P5: prefetch A(t1,q1); stage A(t0') both halves */ \
    RDA(afB, 1, 32768); \
    if (!(LAST)) { \
      STG(Ag + (k0) + 128, lda, 0); \
      STG(Ag + (size_t)128 * lda + (k0) + 128, lda, 8192); \
    } \
    SCH0(); BAR(); QUAD(0, afA, bP2, 0); BAR(); \
    /* P6: wait B(t0') then closing barrier (gates P7 reads) */ \
    BAR(); QUAD(1, afB, bP2, 0); \
    if (!(LAST)) VMC4(); \
    BAR(); SCH0(); \
    /* P7: prefetch B(t0',01); stage B-lo(t1'); wait A(t0') */ \
    if (!(LAST)) { RDBP(bP0, 0, 0); STG(Bg + (k0) + 192, ldb, 32768 + 16384); } \
    SCH0(); BAR(); QUAD(0, afA, bP3, 1); \
    if (!(LAST)) VMC2(); \
    BAR(); SCH0(); \
    /* P8: prefetch B(t0',23)+A(t0',q0); stage B-hi(t1') */ \
    if (!(LAST)) { \
      RDBP(bP1, 1, 0); RDA(afA, 0, 0); \
      STG(Bg + (size_t)128 * ldb + (k0) + 192, ldb, 32768 + 24576); \
    } \
    SCH0(); BAR(); QUAD(1, afB, bP3, 1); BAR(); \
  } while (0)

  // prologue: tile0 full (buf0) + tile1 B halves (buf1)
  STG(Ag, lda, 0);
  STG(Ag + (size_t)128 * lda, lda, 8192);
  STG(Bg, ldb, 16384);
  STG(Bg + (size_t)128 * ldb, ldb, 24576);
  STG(Bg + 64, ldb, 32768 + 16384);
  STG(Bg + (size_t)128 * ldb + 64, ldb, 32768 + 24576);
  VMC4();   // tile0 landed (my wave); barrier proves all waves
  BAR(); SCH0();
  RDA(afA, 0, 0);     // A(t0,q0)
  RDBP(bP0, 0, 0);    // B(t0,01)
  RDBP(bP1, 1, 0);    // B(t0,23)

  const int NI = Kd >> 7;
#pragma unroll 1
  for (int I = 0; I < NI - 1; ++I) ITER(I << 7, 0);
  ITER((NI - 1) << 7, 1);

#undef STG
#undef RDA
#undef RDBP
#undef QUAD
#undef ITER
}

// GEMM1: h[bk] = gelu(x[b] @ w_fc[e]) * w[bk]   -> bf16 [T][H]
__global__ __launch_bounds__(512, 2) void k_gemm1(
    const unsigned short* __restrict__ Xb, const unsigned short* __restrict__ Wfct,
    const int* __restrict__ sel, const float* __restrict__ wv,
    unsigned short* __restrict__ Hout) {
  __shared__ unsigned short LDS[65536];  // 128 KiB
  int flat = blockIdx.x + 16 * (blockIdx.y + 4 * blockIdx.z);   // nwg=1024
  int swz = (flat & 7) * 128 + (flat >> 3);                     // XCD-bijective
  const int bx = swz & 15, by = (swz >> 4) & 3, bk = swz >> 6;
  const int e = sel[bk];
  const float wgt = wv[bk];
  const int row0 = by * 256, col0 = bx * 256;
  v4f acc[8][4];
#pragma unroll
  for (int i = 0; i < 8; ++i)
#pragma unroll
    for (int j = 0; j < 4; ++j) acc[i][j] = (v4f){0.f, 0.f, 0.f, 0.f};

  gemm256(Xb + (size_t)(bk >> 1) * T_ * C_ + (size_t)row0 * C_,
          Wfct + (size_t)e * H_ * C_ + (size_t)col0 * C_,
          C_, C_, C_, LDS, acc);

  const int tid = threadIdx.x;
  const int lane = tid & 63;
  const int w = tid >> 6, wm = w >> 2, wn = w & 3;
  const int rr = lane & 15, q = lane >> 4;
  unsigned short* Co = Hout + (size_t)bk * T_ * H_;
  // padded LDS bounce: [128][264] shorts (row stride 528 B = 16B-aligned; row
  // step of 4 rows -> bank step 16 mod 32 -> 2-way, free)
#pragma unroll
  for (int h = 0; h < 2; ++h) {
    if (wm == h) {
#pragma unroll
      for (int i = 0; i < 8; ++i)
#pragma unroll
        for (int j = 0; j < 4; ++j)
#pragma unroll
          for (int p = 0; p < 4; ++p) {
            int lr = i * 16 + q * 4 + p;
            int lc = wn * 64 + j * 16 + rr;
            float u = acc[i][j][p];
            float y = 0.7978845608028654f * (u + 0.044715f * u * u * u);
            float t = 1.0f - 2.0f / (__expf(2.0f * y) + 1.0f);
            LDS[lr * 264 + lc] = f2bf(0.5f * u * (1.0f + t) * wgt);
          }
    }
    __syncthreads();
#pragma unroll
    for (int m = 0; m < 8; ++m) {
      int idx = m * 512 + tid;
      int row = idx >> 5, cc = idx & 31;
      *(v8s*)&Co[(size_t)(row0 + h * 128 + row) * H_ + col0 + cc * 8] =
          *(const v8s*)&LDS[row * 264 + cc * 8];
    }
    __syncthreads();
  }
}

// GEMM2 (split over the two selected experts): one (b,k) per z-slice.
__global__ __launch_bounds__(512, 2) void k_gemm2(
    const unsigned short* __restrict__ Hin, const unsigned short* __restrict__ Wpt,
    const int* __restrict__ sel, float* __restrict__ P0, float* __restrict__ P1) {
  __shared__ unsigned short LDS[65536];
  int flat = blockIdx.x + 4 * (blockIdx.y + 4 * blockIdx.z);    // nwg=256
  int swz = (flat & 7) * 32 + (flat >> 3);
  const int bx = swz & 3, by = (swz >> 2) & 3, bk = swz >> 4;
  const int b = bk >> 1, k = bk & 1;
  const int e = sel[bk];
  const int row0 = by * 256, col0 = bx * 256;
  v4f acc[8][4];
#pragma unroll
  for (int i = 0; i < 8; ++i)
#pragma unroll
    for (int j = 0; j < 4; ++j) acc[i][j] = (v4f){0.f, 0.f, 0.f, 0.f};

  gemm256(Hin + (size_t)bk * T_ * H_ + (size_t)row0 * H_,
          Wpt + (size_t)e * C_ * H_ + (size_t)col0 * H_,
          H_, H_, H_, LDS, acc);

  const int tid = threadIdx.x;
  const int lane = tid & 63;
  const int w = tid >> 6, wm = w >> 2, wn = w & 3;
  const int rr = lane & 15, q = lane >> 4;
  float* Co = (k == 0 ? P0 : P1) + (size_t)b * T_ * C_;
#pragma unroll
  for (int i = 0; i < 8; ++i) {
    int gr = row0 + wm * 128 + i * 16 + q * 4;
#pragma unroll
    for (int j = 0; j < 4; ++j) {
      int gc = col0 + wn * 64 + j * 16 + rr;
#pragma unroll
      for (int p = 0; p < 4; ++p)
        Co[(size_t)(gr + p) * C_ + gc] = acc[i][j][p];
    }
  }
}

// out += P1
__global__ void k_add(float* __restrict__ out, const float* __restrict__ p1) {
  size_t i = ((size_t)blockIdx.x * 256 + threadIdx.x) * 4;
  v4f a = *(const v4f*)(out + i);
  v4f b = *(const v4f*)(p1 + i);
  a += b;
  *(v4f*)(out + i) = a;
}

// ---------------- launch ----------------

extern "C" void kernel_launch(void* const* d_in, const int* in_sizes, int n_in,
                              void* d_out, int out_size, void* d_ws, size_t ws_size,
                              hipStream_t stream) {
  const float* x   = (const float*)d_in[0];
  const float* rw  = (const float*)d_in[1];
  const float* wfc = (const float*)d_in[2];
  const float* wpj = (const float*)d_in[3];
  float* out = (float*)d_out;
  char* ws = (char*)d_ws;

  float*          part = (float*)(ws + 0);                        // 1 MB
  int*            sel  = (int*)(ws + 1048576);
  float*          wv   = (float*)(ws + 1048576 + 64);
  unsigned short* xb   = (unsigned short*)(ws + 2097152);         // 16 MB
  unsigned short* wfct = (unsigned short*)(ws + 2097152 + 16777216);            // 64 MB
  unsigned short* wpjt = (unsigned short*)(ws + 2097152 + 16777216 + 67108864); // 64 MB
  unsigned short* h    = (unsigned short*)(ws + 2097152 + 16777216 + 2*67108864ll); // 128 MB
  float*          p1   = (float*)(ws + 2097152);  // aliases dead xb+wfct after gemm1

  k_meanpart<<<dim3(B_ * 32), dim3(256), 0, stream>>>(x, part, xb);
  k_router<<<dim3(1), dim3(256), 0, stream>>>(part, rw, sel, wv,
                                              out + (size_t)B_ * T_ * C_);
  k_transpose<<<dim3(H_ / 64, C_ / 64, E_), dim3(256), 0, stream>>>(wfc, wfct, C_, H_);
  k_transpose<<<dim3(C_ / 64, H_ / 64, E_), dim3(256), 0, stream>>>(wpj, wpjt, H_, C_);

  k_gemm1<<<dim3(H_ / 256, T_ / 256, B_ * 2), dim3(512), 0, stream>>>(xb, wfct, sel, wv, h);
  k_gemm2<<<dim3(C_ / 256, T_ / 256, B_ * 2), dim3(512), 0, stream>>>(h, wpjt, sel, out, p1);
  k_add<<<dim3(B_ * T_ * C_ / 4 / 256), dim3(256), 0, stream>>>(out, p1);
}

// Round 4
// 716.688 us; speedup vs baseline: 1.3586x; 1.3586x over previous
//
#include <hip/hip_runtime.h>

#define B_ 8
#define T_ 1024
#define C_ 1024
#define E_ 8
#define H_ 4096

typedef float v4f __attribute__((ext_vector_type(4)));
typedef short v8s __attribute__((ext_vector_type(8)));

__device__ __forceinline__ unsigned short f2bf(float f) {
  union { float f; unsigned int u; } x; x.f = f;
  unsigned int r = x.u + 0x7fffu + ((x.u >> 16) & 1u);
  return (unsigned short)(r >> 16);
}

__device__ __forceinline__ void async_load16(const unsigned short* g, unsigned short* l) {
  __builtin_amdgcn_global_load_lds(
      (const __attribute__((address_space(1))) void*)g,
      (__attribute__((address_space(3))) void*)l, 16, 0, 0);
}

// ---------------- router phase (unchanged) ----------------

__global__ void k_meanpart(const float* __restrict__ x, float* __restrict__ part,
                           unsigned short* __restrict__ xb) {
  int b = blockIdx.x >> 5, tc = blockIdx.x & 31;
  int c4 = threadIdx.x * 4;
  const size_t base = (size_t)b * T_ * C_ + (size_t)tc * 32 * C_ + c4;
  const float* xp = x + base;
  v4f s = {0.f, 0.f, 0.f, 0.f};
  for (int t = 0; t < 32; ++t) {
    v4f v = *(const v4f*)(xp + (size_t)t * C_);
    s += v;
    ushort4 o;
    o.x = f2bf(v.x); o.y = f2bf(v.y); o.z = f2bf(v.z); o.w = f2bf(v.w);
    *(ushort4*)(xb + base + (size_t)t * C_) = o;
  }
  *(v4f*)(part + (size_t)(tc * B_ + b) * C_ + c4) = s;
}

__global__ void k_router(const float* __restrict__ part, const float* __restrict__ rw,
                         int* __restrict__ sel, float* __restrict__ wv,
                         float* __restrict__ loss_out) {
  __shared__ float seq[B_ * C_];
  __shared__ float red[B_ * E_][4];
  __shared__ float pr[B_][E_];
  __shared__ int ss[B_][2];
  const int tid = threadIdx.x;
  for (int idx = tid; idx < B_ * C_; idx += 256) {
    float s = 0.f;
#pragma unroll
    for (int tc = 0; tc < 32; ++tc) s += part[(size_t)tc * B_ * C_ + idx];
    seq[idx] = s * (1.0f / T_);
  }
  __syncthreads();
  {
    int pair = tid >> 2, sub = tid & 3;
    int b = pair >> 3, e = pair & 7;
    float acc = 0.f;
    const float* sp = seq + b * C_ + sub * 256;
    const float* wp = rw + e * C_ + sub * 256;
    for (int c = 0; c < 256; ++c) acc += sp[c] * wp[c];
    red[pair][sub] = acc;
  }
  __syncthreads();
  if (tid < B_ * E_)
    pr[tid >> 3][tid & 7] = red[tid][0] + red[tid][1] + red[tid][2] + red[tid][3];
  __syncthreads();
  if (tid < B_) {
    int b = tid;
    float mx = pr[b][0];
#pragma unroll
    for (int e = 1; e < E_; ++e) mx = fmaxf(mx, pr[b][e]);
    float p[E_]; float sum = 0.f;
#pragma unroll
    for (int e = 0; e < E_; ++e) { p[e] = __expf(pr[b][e] - mx); sum += p[e]; }
    float inv = 1.0f / sum;
#pragma unroll
    for (int e = 0; e < E_; ++e) { p[e] *= inv; pr[b][e] = p[e]; }
    int i0 = 0;
#pragma unroll
    for (int e = 1; e < E_; ++e) if (p[e] > p[i0]) i0 = e;
    int i1 = (i0 == 0) ? 1 : 0;
#pragma unroll
    for (int e = 0; e < E_; ++e) if (e != i0 && p[e] > p[i1]) i1 = e;
    float s2 = p[i0] + p[i1];
    sel[b * 2 + 0] = i0; sel[b * 2 + 1] = i1;
    wv[b * 2 + 0] = p[i0] / s2; wv[b * 2 + 1] = p[i1] / s2;
    ss[b][0] = i0; ss[b][1] = i1;
  }
  __syncthreads();
  if (tid == 0) {
    float loss = 0.f;
    for (int e = 0; e < E_; ++e) {
      float imp = 0.f, ld = 0.f;
      for (int b = 0; b < B_; ++b) {
        imp += pr[b][e];
        ld += ((ss[b][0] == e) || (ss[b][1] == e)) ? 1.f : 0.f;
      }
      loss += (imp / (float)B_) * (ld / (float)B_);
    }
    loss_out[0] = loss * (float)E_;
  }
}

// ---------------- transpose+cast (unchanged) ----------------
__global__ void k_transpose(const float* __restrict__ src, unsigned short* __restrict__ dst,
                            int R, int Cc) {
  __shared__ float tile[64][65];
  const size_t sl = (size_t)blockIdx.z * R * Cc;
  int c0 = blockIdx.x * 64, r0 = blockIdx.y * 64;
  int tx = threadIdx.x & 15, ty = threadIdx.x >> 4;
#pragma unroll
  for (int p = 0; p < 4; ++p) {
    int r = p * 16 + ty;
    v4f v = *(const v4f*)(src + sl + (size_t)(r0 + r) * Cc + c0 + tx * 4);
    tile[r][tx * 4 + 0] = v.x; tile[r][tx * 4 + 1] = v.y;
    tile[r][tx * 4 + 2] = v.z; tile[r][tx * 4 + 3] = v.w;
  }
  __syncthreads();
#pragma unroll
  for (int p = 0; p < 4; ++p) {
    int c = p * 16 + ty;
    int rr = tx * 4;
    ushort4 o;
    o.x = f2bf(tile[rr + 0][c]); o.y = f2bf(tile[rr + 1][c]);
    o.z = f2bf(tile[rr + 2][c]); o.w = f2bf(tile[rr + 3][c]);
    *(ushort4*)(dst + sl + (size_t)(c0 + c) * R + r0 + rr) = o;
  }
}

// ---------------- 128x256 GEMM core: triple-buffered K=64 tiles, ahead-1 frags ------
// 8 waves (2M x 4N), wave tile 64x64 -> acc[4][4] = 64 regs (frees room for the
// register pipeline that spilled at 256x256 in round 3).
// LDS: 3 bufs x 24576 shorts (A[128][64] @ +0, B[256][64] @ +8192), 144 KiB.
// Swizzle: chunk c of row r at phys chunk c^(r&7); staged via pre-swizzled global
// source + linear LDS dest (verified pattern from rounds 0/1).
// Per tile t (ONE barrier, ONE counted vmcnt):
//   RD(slot1 <- t,ks1)            ; frags land >=1 half-tile before their MFMA
//   vmcnt(0)      [waits tile t+1 staging; only its 6 loads are in flight]
//   s_barrier     [all waves waited -> buf(t+1) readable; also proves all waves
//                  drained tile t-1 frag reads -> buf(t-1)=buf(t+2) writable]
//   STG tile t+2 -> buf(t+2)%3    (6 global_load_lds)
//   MFMA(slot0 = t,ks0)
//   RD(slot0 <- t+1,ks0)          [RAW safe: behind this tile's vmcnt+barrier]
//   MFMA(slot1 = t,ks1)
// Ledger: in-flight at each vmcnt = exactly tile (t+1)'s 6 loads (tile t+2's are
// issued after the barrier). Compiler's auto lgkmcnt handles frag RAW (no inline
// ds_read -> rule 18 n/a); sched_barrier(0) pins region boundaries.

#define BAR()  __builtin_amdgcn_s_barrier()
#define SCH0() __builtin_amdgcn_sched_barrier(0)

__device__ __forceinline__ void gemm_core(const unsigned short* __restrict__ Ag,
                                          const unsigned short* __restrict__ Bg,
                                          int lda, int ldb, int Kd,
                                          unsigned short* LDS, v4f (&acc)[4][4]) {
  const int tid = threadIdx.x;
  const int lane = tid & 63;
  const int w = __builtin_amdgcn_readfirstlane(tid >> 6);
  const int wm = w >> 2, wn = w & 3;
  const int rr = lane & 15, q = lane >> 4, s7 = rr & 7;
  const int ck0 = (q ^ s7) * 8, ck1 = ((4 | q) ^ s7) * 8;
  const int aof0 = wm * 4096 + rr * 64;
  const int aof1 = aof0 + 1024, aof2 = aof0 + 2048, aof3 = aof0 + 3072;
  const int bof0 = 8192 + wn * 4096 + rr * 64;
  const int bof1 = bof0 + 1024, bof2 = bof0 + 2048, bof3 = bof0 + 3072;
  const int srow = tid >> 3;
  const int sc8 = ((tid & 7) ^ (srow & 7)) * 8;
  const int ldst = tid * 8;
  v8s a0[4], b0[4], a1[4], b1[4];

#define STG1(goff, ld, loff) async_load16((goff) + (size_t)srow * (ld) + sc8, LDS + (loff) + ldst)
#define STG6(kof, bb) do { \
    STG1(Ag + (kof), lda, (bb)); \
    STG1(Ag + (size_t)64 * lda + (kof), lda, (bb) + 4096); \
    STG1(Bg + (kof), ldb, (bb) + 8192); \
    STG1(Bg + (size_t)64 * ldb + (kof), ldb, (bb) + 12288); \
    STG1(Bg + (size_t)128 * ldb + (kof), ldb, (bb) + 16384); \
    STG1(Bg + (size_t)192 * ldb + (kof), ldb, (bb) + 20480); \
  } while (0)
#define RD8(A_, B_, bb, CK) do { \
    A_[0] = *(const v8s*)&LDS[(bb) + aof0 + (CK)]; \
    A_[1] = *(const v8s*)&LDS[(bb) + aof1 + (CK)]; \
    A_[2] = *(const v8s*)&LDS[(bb) + aof2 + (CK)]; \
    A_[3] = *(const v8s*)&LDS[(bb) + aof3 + (CK)]; \
    B_[0] = *(const v8s*)&LDS[(bb) + bof0 + (CK)]; \
    B_[1] = *(const v8s*)&LDS[(bb) + bof1 + (CK)]; \
    B_[2] = *(const v8s*)&LDS[(bb) + bof2 + (CK)]; \
    B_[3] = *(const v8s*)&LDS[(bb) + bof3 + (CK)]; \
  } while (0)
#define MM16(A_, B_) do { __builtin_amdgcn_s_setprio(1); \
    _Pragma("unroll") for (int i_ = 0; i_ < 4; ++i_) \
    _Pragma("unroll") for (int j_ = 0; j_ < 4; ++j_) \
      acc[i_][j_] = __builtin_amdgcn_mfma_f32_16x16x32_bf16(A_[i_], B_[j_], acc[i_][j_], 0, 0, 0); \
    __builtin_amdgcn_s_setprio(0); } while (0)

  // prologue: stage tiles 0 (buf0) and 1 (buf1); wait tile0; read its ks0 frags
  STG6(0, 0);
  STG6(64, 24576);
  asm volatile("s_waitcnt vmcnt(6)" ::: "memory");
  BAR(); SCH0();
  RD8(a0, b0, 0, ck0);

  int bb0 = 0, bb1 = 24576, bb2 = 49152;
  const int NT = Kd >> 6;
#pragma unroll 1
  for (int t = 0; t < NT; ++t) {
    const bool n1 = (t + 1 < NT), s2 = (t + 2 < NT);
    RD8(a1, b1, bb0, ck1);
    SCH0();
    if (n1) asm volatile("s_waitcnt vmcnt(0)" ::: "memory");
    BAR(); SCH0();
    if (s2) STG6((t + 2) * 64, bb2);
    MM16(a0, b0);
    SCH0();
    if (n1) RD8(a0, b0, bb1, ck0);
    SCH0();
    MM16(a1, b1);
    SCH0();
    int tmp = bb0; bb0 = bb1; bb1 = bb2; bb2 = tmp;
  }
#undef STG1
#undef STG6
#undef RD8
#undef MM16
}

// GEMM1: h[bk] = gelu(x[b] @ w_fc[e]) * w[bk]   -> bf16 [T][H]; tile 128(T)x256(H)
__global__ __launch_bounds__(512, 2) void k_gemm1(
    const unsigned short* __restrict__ Xb, const unsigned short* __restrict__ Wfct,
    const int* __restrict__ sel, const float* __restrict__ wv,
    unsigned short* __restrict__ Hout) {
  __shared__ unsigned short LDS[73728];  // 144 KiB
  int flat = blockIdx.x + 16 * (blockIdx.y + 8 * blockIdx.z);   // nwg = 2048
  int swz = (flat & 7) * 256 + (flat >> 3);                     // XCD-bijective
  const int bx = swz & 15, by = (swz >> 4) & 7, bk = swz >> 7;
  const int e = sel[bk];
  const float wgt = wv[bk];
  const int row0 = by * 128, col0 = bx * 256;
  v4f acc[4][4];
#pragma unroll
  for (int i = 0; i < 4; ++i)
#pragma unroll
    for (int j = 0; j < 4; ++j) acc[i][j] = (v4f){0.f, 0.f, 0.f, 0.f};

  gemm_core(Xb + (size_t)(bk >> 1) * T_ * C_ + (size_t)row0 * C_,
            Wfct + (size_t)e * H_ * C_ + (size_t)col0 * C_,
            C_, C_, C_, LDS, acc);

  const int tid = threadIdx.x;
  const int lane = tid & 63;
  const int w = tid >> 6, wm = w >> 2, wn = w & 3;
  const int rr = lane & 15, q = lane >> 4;
  unsigned short* Co = Hout + (size_t)bk * T_ * H_;
  __syncthreads();
  // full 128x256 tile bounce, stride 264 shorts (row step 4 -> bank step 4, free)
#pragma unroll
  for (int i = 0; i < 4; ++i)
#pragma unroll
    for (int j = 0; j < 4; ++j)
#pragma unroll
      for (int p = 0; p < 4; ++p) {
        int lr = wm * 64 + i * 16 + q * 4 + p;
        int lc = wn * 64 + j * 16 + rr;
        float u = acc[i][j][p];
        float y = 0.7978845608028654f * (u + 0.044715f * u * u * u);
        float t = 1.0f - 2.0f / (__expf(2.0f * y) + 1.0f);
        LDS[lr * 264 + lc] = f2bf(0.5f * u * (1.0f + t) * wgt);
      }
  __syncthreads();
#pragma unroll
  for (int m = 0; m < 8; ++m) {
    int idx = m * 512 + tid;
    int row = idx >> 5, ch = idx & 31;
    *(v8s*)&Co[(size_t)(row0 + row) * H_ + col0 + ch * 8] =
        *(const v8s*)&LDS[row * 264 + ch * 8];
  }
}

// GEMM2: out[b] = h[2b] @ w_proj[e0] + h[2b+1] @ w_proj[e1]  (fused, f32 out)
// tile 128(T) x 256(C); acc accumulates across both expert passes -> no k_add.
__global__ __launch_bounds__(512, 2) void k_gemm2(
    const unsigned short* __restrict__ Hin, const unsigned short* __restrict__ Wpt,
    const int* __restrict__ sel, float* __restrict__ out) {
  __shared__ unsigned short LDS[73728];
  int flat = blockIdx.x + 4 * (blockIdx.y + 8 * blockIdx.z);    // nwg = 256
  int swz = (flat & 7) * 32 + (flat >> 3);
  const int bx = swz & 3, by = (swz >> 2) & 7, b = swz >> 5;
  const int row0 = by * 128, col0 = bx * 256;
  v4f acc[4][4];
#pragma unroll
  for (int i = 0; i < 4; ++i)
#pragma unroll
    for (int j = 0; j < 4; ++j) acc[i][j] = (v4f){0.f, 0.f, 0.f, 0.f};

  gemm_core(Hin + (size_t)(2 * b) * T_ * H_ + (size_t)row0 * H_,
            Wpt + (size_t)sel[2 * b] * C_ * H_ + (size_t)col0 * H_,
            H_, H_, H_, LDS, acc);
  __syncthreads();  // WAR: call1's last frag reads drained before call2 restages
  gemm_core(Hin + (size_t)(2 * b + 1) * T_ * H_ + (size_t)row0 * H_,
            Wpt + (size_t)sel[2 * b + 1] * C_ * H_ + (size_t)col0 * H_,
            H_, H_, H_, LDS, acc);

  const int tid = threadIdx.x;
  const int lane = tid & 63;
  const int w = tid >> 6, wm = w >> 2, wn = w & 3;
  const int rr = lane & 15, q = lane >> 4;
  float* Co = out + (size_t)b * T_ * C_;
#pragma unroll
  for (int i = 0; i < 4; ++i) {
    int gr = row0 + wm * 64 + i * 16 + q * 4;
#pragma unroll
    for (int j = 0; j < 4; ++j) {
      int gc = col0 + wn * 64 + j * 16 + rr;
#pragma unroll
      for (int p = 0; p < 4; ++p)
        Co[(size_t)(gr + p) * C_ + gc] = acc[i][j][p];
    }
  }
}

// ---------------- launch ----------------

extern "C" void kernel_launch(void* const* d_in, const int* in_sizes, int n_in,
                              void* d_out, int out_size, void* d_ws, size_t ws_size,
                              hipStream_t stream) {
  const float* x   = (const float*)d_in[0];
  const float* rw  = (const float*)d_in[1];
  const float* wfc = (const float*)d_in[2];
  const float* wpj = (const float*)d_in[3];
  float* out = (float*)d_out;
  char* ws = (char*)d_ws;

  float*          part = (float*)(ws + 0);                        // 1 MB
  int*            sel  = (int*)(ws + 1048576);
  float*          wv   = (float*)(ws + 1048576 + 64);
  unsigned short* xb   = (unsigned short*)(ws + 2097152);         // 16 MB
  unsigned short* wfct = (unsigned short*)(ws + 2097152 + 16777216);            // 64 MB
  unsigned short* wpjt = (unsigned short*)(ws + 2097152 + 16777216 + 67108864); // 64 MB
  unsigned short* h    = (unsigned short*)(ws + 2097152 + 16777216 + 2*67108864ll); // 128 MB

  k_meanpart<<<dim3(B_ * 32), dim3(256), 0, stream>>>(x, part, xb);
  k_router<<<dim3(1), dim3(256), 0, stream>>>(part, rw, sel, wv,
                                              out + (size_t)B_ * T_ * C_);
  k_transpose<<<dim3(H_ / 64, C_ / 64, E_), dim3(256), 0, stream>>>(wfc, wfct, C_, H_);
  k_transpose<<<dim3(C_ / 64, H_ / 64, E_), dim3(256), 0, stream>>>(wpj, wpjt, H_, C_);

  k_gemm1<<<dim3(H_ / 256, T_ / 128, B_ * 2), dim3(512), 0, stream>>>(xb, wfct, sel, wv, h);
  k_gemm2<<<dim3(C_ / 256, T_ / 128, B_), dim3(512), 0, stream>>>(h, wpjt, sel, out);
}

// Round 5
// 680.444 us; speedup vs baseline: 1.4310x; 1.0533x over previous
//
#include <hip/hip_runtime.h>

#define B_ 8
#define T_ 1024
#define C_ 1024
#define E_ 8
#define H_ 4096

typedef float v4f __attribute__((ext_vector_type(4)));
typedef short v8s __attribute__((ext_vector_type(8)));

__device__ __forceinline__ unsigned short f2bf(float f) {
  union { float f; unsigned int u; } x; x.f = f;
  unsigned int r = x.u + 0x7fffu + ((x.u >> 16) & 1u);
  return (unsigned short)(r >> 16);
}

__device__ __forceinline__ void async_load16(const unsigned short* g, unsigned short* l) {
  __builtin_amdgcn_global_load_lds(
      (const __attribute__((address_space(1))) void*)g,
      (__attribute__((address_space(3))) void*)l, 16, 0, 0);
}

// ---------------- router phase (unchanged) ----------------

__global__ void k_meanpart(const float* __restrict__ x, float* __restrict__ part,
                           unsigned short* __restrict__ xb) {
  int b = blockIdx.x >> 5, tc = blockIdx.x & 31;
  int c4 = threadIdx.x * 4;
  const size_t base = (size_t)b * T_ * C_ + (size_t)tc * 32 * C_ + c4;
  const float* xp = x + base;
  v4f s = {0.f, 0.f, 0.f, 0.f};
  for (int t = 0; t < 32; ++t) {
    v4f v = *(const v4f*)(xp + (size_t)t * C_);
    s += v;
    ushort4 o;
    o.x = f2bf(v.x); o.y = f2bf(v.y); o.z = f2bf(v.z); o.w = f2bf(v.w);
    *(ushort4*)(xb + base + (size_t)t * C_) = o;
  }
  *(v4f*)(part + (size_t)(tc * B_ + b) * C_ + c4) = s;
}

__global__ void k_router(const float* __restrict__ part, const float* __restrict__ rw,
                         int* __restrict__ sel, float* __restrict__ wv,
                         float* __restrict__ loss_out) {
  __shared__ float seq[B_ * C_];
  __shared__ float red[B_ * E_][4];
  __shared__ float pr[B_][E_];
  __shared__ int ss[B_][2];
  const int tid = threadIdx.x;
  for (int idx = tid; idx < B_ * C_; idx += 256) {
    float s = 0.f;
#pragma unroll
    for (int tc = 0; tc < 32; ++tc) s += part[(size_t)tc * B_ * C_ + idx];
    seq[idx] = s * (1.0f / T_);
  }
  __syncthreads();
  {
    int pair = tid >> 2, sub = tid & 3;
    int b = pair >> 3, e = pair & 7;
    float acc = 0.f;
    const float* sp = seq + b * C_ + sub * 256;
    const float* wp = rw + e * C_ + sub * 256;
    for (int c = 0; c < 256; ++c) acc += sp[c] * wp[c];
    red[pair][sub] = acc;
  }
  __syncthreads();
  if (tid < B_ * E_)
    pr[tid >> 3][tid & 7] = red[tid][0] + red[tid][1] + red[tid][2] + red[tid][3];
  __syncthreads();
  if (tid < B_) {
    int b = tid;
    float mx = pr[b][0];
#pragma unroll
    for (int e = 1; e < E_; ++e) mx = fmaxf(mx, pr[b][e]);
    float p[E_]; float sum = 0.f;
#pragma unroll
    for (int e = 0; e < E_; ++e) { p[e] = __expf(pr[b][e] - mx); sum += p[e]; }
    float inv = 1.0f / sum;
#pragma unroll
    for (int e = 0; e < E_; ++e) { p[e] *= inv; pr[b][e] = p[e]; }
    int i0 = 0;
#pragma unroll
    for (int e = 1; e < E_; ++e) if (p[e] > p[i0]) i0 = e;
    int i1 = (i0 == 0) ? 1 : 0;
#pragma unroll
    for (int e = 0; e < E_; ++e) if (e != i0 && p[e] > p[i1]) i1 = e;
    float s2 = p[i0] + p[i1];
    sel[b * 2 + 0] = i0; sel[b * 2 + 1] = i1;
    wv[b * 2 + 0] = p[i0] / s2; wv[b * 2 + 1] = p[i1] / s2;
    ss[b][0] = i0; ss[b][1] = i1;
  }
  __syncthreads();
  if (tid == 0) {
    float loss = 0.f;
    for (int e = 0; e < E_; ++e) {
      float imp = 0.f, ld = 0.f;
      for (int b = 0; b < B_; ++b) {
        imp += pr[b][e];
        ld += ((ss[b][0] == e) || (ss[b][1] == e)) ? 1.f : 0.f;
      }
      loss += (imp / (float)B_) * (ld / (float)B_);
    }
    loss_out[0] = loss * (float)E_;
  }
}

// ---------------- transpose+cast (unchanged) ----------------
__global__ void k_transpose(const float* __restrict__ src, unsigned short* __restrict__ dst,
                            int R, int Cc) {
  __shared__ float tile[64][65];
  const size_t sl = (size_t)blockIdx.z * R * Cc;
  int c0 = blockIdx.x * 64, r0 = blockIdx.y * 64;
  int tx = threadIdx.x & 15, ty = threadIdx.x >> 4;
#pragma unroll
  for (int p = 0; p < 4; ++p) {
    int r = p * 16 + ty;
    v4f v = *(const v4f*)(src + sl + (size_t)(r0 + r) * Cc + c0 + tx * 4);
    tile[r][tx * 4 + 0] = v.x; tile[r][tx * 4 + 1] = v.y;
    tile[r][tx * 4 + 2] = v.z; tile[r][tx * 4 + 3] = v.w;
  }
  __syncthreads();
#pragma unroll
  for (int p = 0; p < 4; ++p) {
    int c = p * 16 + ty;
    int rr = tx * 4;
    ushort4 o;
    o.x = f2bf(tile[rr + 0][c]); o.y = f2bf(tile[rr + 1][c]);
    o.z = f2bf(tile[rr + 2][c]); o.w = f2bf(tile[rr + 3][c]);
    *(ushort4*)(dst + sl + (size_t)(c0 + c) * R + r0 + rr) = o;
  }
}

// ---------------- 128x256 GEMM core: triple-buffered K=64 tiles ----------------
// 8 waves (2M x 4N), wave tile 64x64, acc[4][4]=64 regs.  LDS: 3 bufs x 24576
// shorts (A[128][64] @ +0, B[256][64] @ +8192), 144 KiB.  Swizzle: chunk c of
// row r at phys chunk c^(r&7), staged via pre-swizzled global source + linear
// LDS dest (addressing identical to the round-4 passing kernel).
//
// Round-5 schedule change (latency coverage): STG6(t+2) is issued at the TOP of
// iteration t, BEFORE the counted wait, so each tile's staging loads get a full
// iteration (~>HBM latency) in flight before their vmcnt.
// Per iteration:
//   RD8(a1,b1 <- buf t, ks1)     [buf t validated at iter t-1's wait+BAR]
//   STG6(t+2 -> buf(t-1))        [WAR: buf(t-1) reads all issued before iter
//                                 t-1's BAR; this STG is after that BAR]
//   vmcnt(6)                     [drains tile t+1's 6; t+2's 6 stay in flight]
//   BAR; sched_barrier(0)        [all waves waited -> buf(t+1) readable;
//                                 SCH0 stops reads hoisting above BAR]
//   MM16(a0,b0)  [frags from prev iter]
//   RD8(a0,b0 <- buf t+1, ks0)   [safe: behind wait+BAR]
//   MM16(a1,b1)                  [auto-lgkm waits top RD8 only]
// Edges: t=NT-2 no STG, vmcnt(0) drains last tile; t=NT-1 no STG/no mid-RD8,
// vmcnt(0) free.  Ledger closed: outstanding at each counted wait = 12.

#define BAR()  __builtin_amdgcn_s_barrier()
#define SCH0() __builtin_amdgcn_sched_barrier(0)

__device__ __forceinline__ void gemm_core(const unsigned short* __restrict__ Ag,
                                          const unsigned short* __restrict__ Bg,
                                          int lda, int ldb, int Kd,
                                          unsigned short* LDS, v4f (&acc)[4][4]) {
  const int tid = threadIdx.x;
  const int lane = tid & 63;
  const int w = __builtin_amdgcn_readfirstlane(tid >> 6);
  const int wm = w >> 2, wn = w & 3;
  const int rr = lane & 15, q = lane >> 4, s7 = rr & 7;
  const int ck0 = (q ^ s7) * 8, ck1 = ((4 | q) ^ s7) * 8;
  const int aof0 = wm * 4096 + rr * 64;
  const int aof1 = aof0 + 1024, aof2 = aof0 + 2048, aof3 = aof0 + 3072;
  const int bof0 = 8192 + wn * 4096 + rr * 64;
  const int bof1 = bof0 + 1024, bof2 = bof0 + 2048, bof3 = bof0 + 3072;
  const int srow = tid >> 3;
  const int sc8 = ((tid & 7) ^ (srow & 7)) * 8;
  const int ldst = tid * 8;
  // running global pointers (advanced +64 shorts per staged tile)
  const unsigned short* ga0 = Ag + (size_t)srow * lda + sc8;
  const unsigned short* ga1 = ga0 + (size_t)64 * lda;
  const unsigned short* gb0 = Bg + (size_t)srow * ldb + sc8;
  const unsigned short* gb1 = gb0 + (size_t)64 * ldb;
  const unsigned short* gb2 = gb0 + (size_t)128 * ldb;
  const unsigned short* gb3 = gb0 + (size_t)192 * ldb;
  v8s a0[4], b0[4], a1[4], b1[4];

#define STG6(kof, bb) do { \
    async_load16(ga0 + (kof), LDS + (bb) + ldst); \
    async_load16(ga1 + (kof), LDS + (bb) + 4096 + ldst); \
    async_load16(gb0 + (kof), LDS + (bb) + 8192 + ldst); \
    async_load16(gb1 + (kof), LDS + (bb) + 12288 + ldst); \
    async_load16(gb2 + (kof), LDS + (bb) + 16384 + ldst); \
    async_load16(gb3 + (kof), LDS + (bb) + 20480 + ldst); \
  } while (0)
#define RD8(A_, B_, bb, CK) do { \
    A_[0] = *(const v8s*)&LDS[(bb) + aof0 + (CK)]; \
    A_[1] = *(const v8s*)&LDS[(bb) + aof1 + (CK)]; \
    A_[2] = *(const v8s*)&LDS[(bb) + aof2 + (CK)]; \
    A_[3] = *(const v8s*)&LDS[(bb) + aof3 + (CK)]; \
    B_[0] = *(const v8s*)&LDS[(bb) + bof0 + (CK)]; \
    B_[1] = *(const v8s*)&LDS[(bb) + bof1 + (CK)]; \
    B_[2] = *(const v8s*)&LDS[(bb) + bof2 + (CK)]; \
    B_[3] = *(const v8s*)&LDS[(bb) + bof3 + (CK)]; \
  } while (0)
#define MM16(A_, B_) do { __builtin_amdgcn_s_setprio(1); \
    _Pragma("unroll") for (int i_ = 0; i_ < 4; ++i_) \
    _Pragma("unroll") for (int j_ = 0; j_ < 4; ++j_) \
      acc[i_][j_] = __builtin_amdgcn_mfma_f32_16x16x32_bf16(A_[i_], B_[j_], acc[i_][j_], 0, 0, 0); \
    __builtin_amdgcn_s_setprio(0); } while (0)

  // prologue: stage tiles 0 (buf0) and 1 (buf1); wait tile0; read its ks0 frags
  STG6(0, 0);
  STG6(64, 24576);
  ga0 += 128; ga1 += 128; gb0 += 128; gb1 += 128; gb2 += 128; gb3 += 128;
  asm volatile("s_waitcnt vmcnt(6)" ::: "memory");
  BAR(); SCH0();
  RD8(a0, b0, 0, ck0);

  int bb0 = 0, bb1 = 24576, bb2 = 49152;
  const int NT = Kd >> 6;
#pragma unroll 1
  for (int t = 0; t < NT; ++t) {
    RD8(a1, b1, bb0, ck1);
    if (t + 2 < NT) {
      STG6(0, bb2);
      ga0 += 64; ga1 += 64; gb0 += 64; gb1 += 64; gb2 += 64; gb3 += 64;
      asm volatile("s_waitcnt vmcnt(6)" ::: "memory");
    } else {
      asm volatile("s_waitcnt vmcnt(0)" ::: "memory");
    }
    BAR(); SCH0();
    MM16(a0, b0);
    if (t + 1 < NT) RD8(a0, b0, bb1, ck0);
    MM16(a1, b1);
    int tmp = bb0; bb0 = bb1; bb1 = bb2; bb2 = tmp;
  }
#undef STG6
#undef RD8
#undef MM16
}

// GEMM1: h[bk] = gelu(x[b] @ w_fc[e]) * w[bk]   -> bf16 [T][H]; tile 128(T)x256(H)
__global__ __launch_bounds__(512, 2) void k_gemm1(
    const unsigned short* __restrict__ Xb, const unsigned short* __restrict__ Wfct,
    const int* __restrict__ sel, const float* __restrict__ wv,
    unsigned short* __restrict__ Hout) {
  __shared__ unsigned short LDS[73728];  // 144 KiB
  int flat = blockIdx.x + 16 * (blockIdx.y + 8 * blockIdx.z);   // nwg = 2048
  int swz = (flat & 7) * 256 + (flat >> 3);                     // XCD-bijective
  const int bx = swz & 15, by = (swz >> 4) & 7, bk = swz >> 7;
  const int e = sel[bk];
  const float wgt = wv[bk];
  const int row0 = by * 128, col0 = bx * 256;
  v4f acc[4][4];
#pragma unroll
  for (int i = 0; i < 4; ++i)
#pragma unroll
    for (int j = 0; j < 4; ++j) acc[i][j] = (v4f){0.f, 0.f, 0.f, 0.f};

  gemm_core(Xb + (size_t)(bk >> 1) * T_ * C_ + (size_t)row0 * C_,
            Wfct + (size_t)e * H_ * C_ + (size_t)col0 * C_,
            C_, C_, C_, LDS, acc);

  const int tid = threadIdx.x;
  const int lane = tid & 63;
  const int w = tid >> 6, wm = w >> 2, wn = w & 3;
  const int rr = lane & 15, q = lane >> 4;
  unsigned short* Co = Hout + (size_t)bk * T_ * H_;
  __syncthreads();
  // full 128x256 tile bounce, stride 264 shorts (row step 4 -> bank step 4, free)
#pragma unroll
  for (int i = 0; i < 4; ++i)
#pragma unroll
    for (int j = 0; j < 4; ++j)
#pragma unroll
      for (int p = 0; p < 4; ++p) {
        int lr = wm * 64 + i * 16 + q * 4 + p;
        int lc = wn * 64 + j * 16 + rr;
        float u = acc[i][j][p];
        float y = 0.7978845608028654f * (u + 0.044715f * u * u * u);
        float t = 1.0f - 2.0f / (__expf(2.0f * y) + 1.0f);
        LDS[lr * 264 + lc] = f2bf(0.5f * u * (1.0f + t) * wgt);
      }
  __syncthreads();
#pragma unroll
  for (int m = 0; m < 8; ++m) {
    int idx = m * 512 + tid;
    int row = idx >> 5, ch = idx & 31;
    *(v8s*)&Co[(size_t)(row0 + row) * H_ + col0 + ch * 8] =
        *(const v8s*)&LDS[row * 264 + ch * 8];
  }
}

// GEMM2: out[b] = h[2b] @ w_proj[e0] + h[2b+1] @ w_proj[e1]  (fused, f32 out)
// tile 128(T) x 256(C); acc accumulates across both expert passes -> no k_add.
__global__ __launch_bounds__(512, 2) void k_gemm2(
    const unsigned short* __restrict__ Hin, const unsigned short* __restrict__ Wpt,
    const int* __restrict__ sel, float* __restrict__ out) {
  __shared__ unsigned short LDS[73728];
  int flat = blockIdx.x + 4 * (blockIdx.y + 8 * blockIdx.z);    // nwg = 256
  int swz = (flat & 7) * 32 + (flat >> 3);
  const int bx = swz & 3, by = (swz >> 2) & 7, b = swz >> 5;
  const int row0 = by * 128, col0 = bx * 256;
  v4f acc[4][4];
#pragma unroll
  for (int i = 0; i < 4; ++i)
#pragma unroll
    for (int j = 0; j < 4; ++j) acc[i][j] = (v4f){0.f, 0.f, 0.f, 0.f};

  gemm_core(Hin + (size_t)(2 * b) * T_ * H_ + (size_t)row0 * H_,
            Wpt + (size_t)sel[2 * b] * C_ * H_ + (size_t)col0 * H_,
            H_, H_, H_, LDS, acc);
  __syncthreads();  // WAR: call1's frag reads drained before call2 restages
  gemm_core(Hin + (size_t)(2 * b + 1) * T_ * H_ + (size_t)row0 * H_,
            Wpt + (size_t)sel[2 * b + 1] * C_ * H_ + (size_t)col0 * H_,
            H_, H_, H_, LDS, acc);

  const int tid = threadIdx.x;
  const int lane = tid & 63;
  const int w = tid >> 6, wm = w >> 2, wn = w & 3;
  const int rr = lane & 15, q = lane >> 4;
  float* Co = out + (size_t)b * T_ * C_;
#pragma unroll
  for (int i = 0; i < 4; ++i) {
    int gr = row0 + wm * 64 + i * 16 + q * 4;
#pragma unroll
    for (int j = 0; j < 4; ++j) {
      int gc = col0 + wn * 64 + j * 16 + rr;
#pragma unroll
      for (int p = 0; p < 4; ++p)
        Co[(size_t)(gr + p) * C_ + gc] = acc[i][j][p];
    }
  }
}

// ---------------- launch ----------------

extern "C" void kernel_launch(void* const* d_in, const int* in_sizes, int n_in,
                              void* d_out, int out_size, void* d_ws, size_t ws_size,
                              hipStream_t stream) {
  const float* x   = (const float*)d_in[0];
  const float* rw  = (const float*)d_in[1];
  const float* wfc = (const float*)d_in[2];
  const float* wpj = (const float*)d_in[3];
  float* out = (float*)d_out;
  char* ws = (char*)d_ws;

  float*          part = (float*)(ws + 0);                        // 1 MB
  int*            sel  = (int*)(ws + 1048576);
  float*          wv   = (float*)(ws + 1048576 + 64);
  unsigned short* xb   = (unsigned short*)(ws + 2097152);         // 16 MB
  unsigned short* wfct = (unsigned short*)(ws + 2097152 + 16777216);            // 64 MB
  unsigned short* wpjt = (unsigned short*)(ws + 2097152 + 16777216 + 67108864); // 64 MB
  unsigned short* h    = (unsigned short*)(ws + 2097152 + 16777216 + 2*67108864ll); // 128 MB

  k_meanpart<<<dim3(B_ * 32), dim3(256), 0, stream>>>(x, part, xb);
  k_router<<<dim3(1), dim3(256), 0, stream>>>(part, rw, sel, wv,
                                              out + (size_t)B_ * T_ * C_);
  k_transpose<<<dim3(H_ / 64, C_ / 64, E_), dim3(256), 0, stream>>>(wfc, wfct, C_, H_);
  k_transpose<<<dim3(C_ / 64, H_ / 64, E_), dim3(256), 0, stream>>>(wpj, wpjt, H_, C_);

  k_gemm1<<<dim3(H_ / 256, T_ / 128, B_ * 2), dim3(512), 0, stream>>>(xb, wfct, sel, wv, h);
  k_gemm2<<<dim3(C_ / 256, T_ / 128, B_), dim3(512), 0, stream>>>(h, wpjt, sel, out);
}